// Round 1
// baseline (277.594 us; speedup 1.0000x reference)
//
#include <hip/hip_runtime.h>

// EdgeMLP: f = (relu(x@W1+b1)@W2+b2) for both edge sets, then masked pairwise
// cosine similarity out[i][j] = (cls1[i]==cls2[j]) * dot(f1_hat[i], f2_hat[j]).
// Strategy: stage 1 computes normalized features (bf16) + int labels into ws;
// stage 2 does one mfma_f32_16x16x32_bf16 per 16x16 output tile (K=32 == feature dim).
// Output 8192x8192 fp32 = 256MB -> HBM-write-bound.

typedef __bf16 bf16x8 __attribute__((ext_vector_type(8)));
typedef float floatx4 __attribute__((ext_vector_type(4)));

__global__ __launch_bounds__(256) void mlp_norm_kernel(
    const float* __restrict__ e1, const float* __restrict__ e2,
    const float* __restrict__ W1, const float* __restrict__ b1,
    const float* __restrict__ W2, const float* __restrict__ b2,
    __bf16* __restrict__ f1b, __bf16* __restrict__ f2b,
    int* __restrict__ cls1, int* __restrict__ cls2, int N1, int N2)
{
    __shared__ float sW1[192];
    __shared__ float sb1[64];
    __shared__ float sW2[2048];
    __shared__ float sb2[32];
    for (int i = threadIdx.x; i < 192; i += 256) sW1[i] = W1[i];
    if (threadIdx.x < 64) sb1[threadIdx.x] = b1[threadIdx.x];
    for (int i = threadIdx.x; i < 2048; i += 256) sW2[i] = W2[i];
    if (threadIdx.x < 32) sb2[threadIdx.x] = b2[threadIdx.x];
    __syncthreads();

    int t = blockIdx.x * 256 + threadIdx.x;
    if (t >= N1 + N2) return;

    const float* src;
    __bf16* fout;
    int* cout;
    int row;
    if (t < N1) { row = t;      src = e1 + (size_t)row * 4; fout = f1b; cout = cls1; }
    else        { row = t - N1; src = e2 + (size_t)row * 4; fout = f2b; cout = cls2; }

    float x0 = src[0], x1 = src[1], x2 = src[2];
    int lbl = (int)src[3];

    float f[32];
#pragma unroll
    for (int k = 0; k < 32; ++k) f[k] = sb2[k];

    for (int j = 0; j < 64; ++j) {
        float h = fmaf(x0, sW1[j], fmaf(x1, sW1[64 + j], fmaf(x2, sW1[128 + j], sb1[j])));
        h = fmaxf(h, 0.0f);
#pragma unroll
        for (int k = 0; k < 32; ++k) f[k] = fmaf(h, sW2[j * 32 + k], f[k]);
    }

    float ss = 0.0f;
#pragma unroll
    for (int k = 0; k < 32; ++k) ss = fmaf(f[k], f[k], ss);
    float n = sqrtf(ss);
    float scale = (n > 1e-20f) ? (1.0f / n) : 0.0f;

    __bf16* dst = fout + (size_t)row * 32;
#pragma unroll
    for (int k = 0; k < 32; ++k) dst[k] = (__bf16)(f[k] * scale);
    cout[row] = lbl;
}

// Each wave: one 16-row strip x 512-col span (32 tiles of 16x16, one MFMA each).
// A/B fragment layout (verified m89/m118): row = lane&15, k = (lane>>4)*8 + j
// -> both fragments are single 16B loads from the [N,32] bf16 feature arrays.
// C/D layout: col = lane&15, row = (lane>>4)*4 + reg.
__global__ __launch_bounds__(256) void pair_cos_kernel(
    const __bf16* __restrict__ f1b, const __bf16* __restrict__ f2b,
    const int* __restrict__ cls1, const int* __restrict__ cls2,
    float* __restrict__ out, int N2, int ncg)
{
    const int lane = threadIdx.x & 63;
    const int wid = blockIdx.x * 4 + (threadIdx.x >> 6);
    const int istrip = wid / ncg;
    const int cg = wid - istrip * ncg;
    const int i0 = istrip * 16;
    const int j0 = cg * 512;
    const int r16 = lane & 15;
    const int q = lane >> 4;

    bf16x8 a = *(const bf16x8*)(f1b + (size_t)(i0 + r16) * 32 + q * 8);
    int4 c1 = *(const int4*)(cls1 + i0 + q * 4);

    const size_t row_base = (size_t)(i0 + q * 4) * N2;

#pragma unroll 4
    for (int tIdx = 0; tIdx < 32; ++tIdx) {
        int j = j0 + tIdx * 16;
        bf16x8 b = *(const bf16x8*)(f2b + (size_t)(j + r16) * 32 + q * 8);
        int c2 = cls2[j + r16];

        floatx4 acc = {0.0f, 0.0f, 0.0f, 0.0f};
        floatx4 d = __builtin_amdgcn_mfma_f32_16x16x32_bf16(a, b, acc, 0, 0, 0);

        float* outp = out + row_base + j + r16;
        outp[0]            = (c1.x == c2) ? d[0] : 0.0f;
        outp[(size_t)N2]   = (c1.y == c2) ? d[1] : 0.0f;
        outp[(size_t)N2*2] = (c1.z == c2) ? d[2] : 0.0f;
        outp[(size_t)N2*3] = (c1.w == c2) ? d[3] : 0.0f;
    }
}

extern "C" void kernel_launch(void* const* d_in, const int* in_sizes, int n_in,
                              void* d_out, int out_size, void* d_ws, size_t ws_size,
                              hipStream_t stream) {
    const float* e1 = (const float*)d_in[0];
    const float* e2 = (const float*)d_in[1];
    const float* W1 = (const float*)d_in[2];
    const float* b1 = (const float*)d_in[3];
    const float* W2 = (const float*)d_in[4];
    const float* b2 = (const float*)d_in[5];
    float* out = (float*)d_out;

    const int N1 = in_sizes[0] / 4;  // 8192
    const int N2 = in_sizes[1] / 4;  // 8192

    char* ws = (char*)d_ws;
    __bf16* f1b = (__bf16*)ws;                                   // N1*32 bf16
    __bf16* f2b = (__bf16*)(ws + (size_t)N1 * 64);               // N2*32 bf16
    int* cls1 = (int*)(ws + (size_t)(N1 + N2) * 64);             // N1 ints
    int* cls2 = cls1 + N1;                                       // N2 ints

    int nrows = N1 + N2;
    mlp_norm_kernel<<<(nrows + 255) / 256, 256, 0, stream>>>(
        e1, e2, W1, b1, W2, b2, f1b, f2b, cls1, cls2, N1, N2);

    int ncg = N2 / 512;                 // 16 col-groups of 512
    int nwaves = (N1 / 16) * ncg;       // 8192 waves
    pair_cos_kernel<<<nwaves / 4, 256, 0, stream>>>(
        f1b, f2b, cls1, cls2, out, N2, ncg);
}